// Round 11
// baseline (97.099 us; speedup 1.0000x reference)
//
#include <hip/hip_runtime.h>

// LogisticRegressionRBF: out[k] = sigmoid( sum_n w[n]*exp(-||x_k - c_n||^2) + b )
// K=65536, N=4096, M=64. fp32 in/out.
//
// R18: BRANCH-FREE hot loop + deferred verification. Post-mortem chain:
// prefetch depth (R13), VALU diet (R13), de-convoy (R14), occupancy (R15/16:
// TLP-sensitive but reg-capped at ~16 waves/CU), LDS staging (R17) -- all
// neutral; main pinned at ~30 us vs ~9 us overlapped floor (MFMA-busy 6-7,
// VALU-busy ~9-13, HBM ~10 MB). Remaining serializer: the per-chunk
// DIVERGENT SCREEN -- exec-mask region with LDS atomics between chunk c's
// MFMAs and chunk c+1's; hipcc won't hoist MFMAs across it, so every chunk
// pays MFMA latency + fmax tree + ballot serially (~130+ cyc x 32).
// Fix: hot loop computes ONLY run = max_c(mx_c - tq_c) (MFMA + fmax tree +
// sub/max; no ballot/branch/atomics -> freely pipelinable). After the loop,
// ~1% of waves (__any(run>0)) re-run all 32 chunks through the exact R13
// screen+atomic path (L2-hot, deterministic MFMA -> identical output).
// mx - tq > 0 <=> mx > tq exactly (operand exponents >= -20, no FTZ hazard).
// Kept: R13 ping-pong direct-L2 loads, packed bf16 meta, tight screen,
// barrier-free loop. Regs ~120 (same 16-wave band). Tripwire: WRITE_SIZE.

#define KOBS 65536
#define NCENT 4096
#define MFEAT 64
#define NCHUNK 32                    // 4096 / 128 centers per chunk

#define SCALE_A 2.8853900817779268f  // 2*log2(e)
#define QS      1.4426950408889634f  // log2(e)
#define TSKIP   -60.0f

typedef __attribute__((ext_vector_type(4)))  float float4v;
typedef __attribute__((ext_vector_type(16))) float float16v;
typedef __attribute__((ext_vector_type(8)))  int   int8v;

#if __has_builtin(__builtin_amdgcn_exp2f)
#define EXP2F(x) __builtin_amdgcn_exp2f(x)
#else
#define EXP2F(x) exp2f(x)
#endif

static __device__ inline unsigned f2bfu(float f) {
    unsigned u = __float_as_uint(f);
    return (u + 0x7fffu + ((u >> 16) & 1u)) >> 16;
}

#define MFMA(A, B, C) __builtin_amdgcn_mfma_scale_f32_32x32x64_f8f6f4( \
    (A), (B), (C), 0, 0, 0, 0x7f7f7f7f, 0, 0x7f7f7f7f)

// 16-value max tree (max3-fusable triples)
#define MAX16(DST, AV) do {                                        \
    float t0_ = fmaxf(fmaxf((AV)[0],  (AV)[1]),  (AV)[2]);         \
    float t1_ = fmaxf(fmaxf((AV)[3],  (AV)[4]),  (AV)[5]);         \
    float t2_ = fmaxf(fmaxf((AV)[6],  (AV)[7]),  (AV)[8]);         \
    float t3_ = fmaxf(fmaxf((AV)[9],  (AV)[10]), (AV)[11]);        \
    float t4_ = fmaxf(fmaxf((AV)[12], (AV)[13]), (AV)[14]);        \
    DST = fmaxf(fmaxf(fmaxf(t0_, t1_), t2_),                       \
                fmaxf(fmaxf(t3_, t4_), (AV)[15]));                 \
} while (0)

// ================================ prep =====================================
// Blocks [0,128): transpose+quantize xb fp32 -> fp8 e4m3 B-fragments.
// Blocks [128,1152): hcw[n] = { bf16(TSKIP + log2e*||c_n||^2) | bf16(w[n]) }.
__global__ __launch_bounds__(256) void rbf_prep(
    const float* __restrict__ xb, const float* __restrict__ w,
    char* __restrict__ cb, unsigned* __restrict__ hcw) {
    const int bid = blockIdx.x;
    const int tid = threadIdx.x;
    if (bid < 128) {
        const int o      = bid * 256 + tid;   // (center, k-octet), [0, 32768)
        const int col    = o >> 3;            // center index
        const int joct   = o & 7;             // k0 = joct*8
        const int c      = col >> 7;          // chunk
        const int w4     = (col >> 5) & 3;    // wave-quarter within chunk
        const int lanelo = col & 31;
        const int l      = lanelo + (joct >> 2) * 32;  // lane (k-half select)
        const int j0     = (joct & 3) * 8;             // byte offset in 32B
        const float* src = xb + col * MFEAT + joct * 8;
        float4v v0 = *(const float4v*)(src);
        float4v v1 = *(const float4v*)(src + 4);
        int lo = __builtin_amdgcn_cvt_pk_fp8_f32(v0[0], v0[1], 0, false);
        lo     = __builtin_amdgcn_cvt_pk_fp8_f32(v0[2], v0[3], lo, true);
        int hi = __builtin_amdgcn_cvt_pk_fp8_f32(v1[0], v1[1], 0, false);
        hi     = __builtin_amdgcn_cvt_pk_fp8_f32(v1[2], v1[3], hi, true);
        unsigned long long pk = (unsigned long long)(unsigned)lo |
                                ((unsigned long long)(unsigned)hi << 32);
        *(unsigned long long*)(cb + (size_t)((c * 4 + w4) * 64 + l) * 32 + j0) = pk;
    } else {
        const int row  = (bid - 128) * 4 + (tid >> 6);
        const int lane = tid & 63;
        float v = xb[row * MFEAT + lane];
        float s = v * v;
        #pragma unroll
        for (int off = 32; off > 0; off >>= 1) s += __shfl_xor(s, off, 64);
        if (lane == 0)
            hcw[row] = (f2bfu(TSKIP + QS * s) << 16) | f2bfu(w[row]);
    }
}

// ================================ main =====================================
// grid 512 x block 512. Block: 128 output rows.
// Wave wv: rt = wv>>2 row-tile (64 rows), wq = wv&3 center quarter.
__global__ __launch_bounds__(512, 4) void rbf_main(
    const float* __restrict__ x, const char* __restrict__ cb,
    const unsigned* __restrict__ hcw, const float* __restrict__ bptr,
    float* __restrict__ out) {
    __shared__ float x2s[128];
    __shared__ float zl[128];

    const int tid  = threadIdx.x;
    const int wv   = tid >> 6;
    const int lane = tid & 63;
    const int ll   = lane & 31;
    const int lh   = lane >> 5;
    const int rt   = wv >> 2;
    const int wq   = wv & 3;
    const int bid  = (int)blockIdx.x;

    if (tid < 128) zl[tid] = 0.0f;

    // ---- A fragments (fp8, pre-scaled by 2*log2e) + row norms ----
    // A-frag layout 32x32x64: lane l holds row l&31, k = (l>>5)*32 + byte.
    const int r0e = bid * 128 + rt * 64;
    int8v af0, af1;
    #pragma unroll
    for (int t = 0; t < 2; ++t) {
        const float* xr = x + (size_t)(r0e + t * 32 + ll) * MFEAT + lh * 32;
        int8v a;
        float ss = 0.0f;
        #pragma unroll
        for (int rg = 0; rg < 8; ++rg) {
            float4v v = *(const float4v*)(xr + rg * 4);
            ss = fmaf(v[0], v[0], ss); ss = fmaf(v[1], v[1], ss);
            ss = fmaf(v[2], v[2], ss); ss = fmaf(v[3], v[3], ss);
            int pk = __builtin_amdgcn_cvt_pk_fp8_f32(
                SCALE_A * v[0], SCALE_A * v[1], 0, false);
            pk = __builtin_amdgcn_cvt_pk_fp8_f32(
                SCALE_A * v[2], SCALE_A * v[3], pk, true);
            a[rg] = pk;
        }
        ss += __shfl_xor(ss, 32, 64);   // partner lane has other k-half
        if (t == 0) af0 = a; else af1 = a;
        if (wq == 0 && lh == 0) x2s[rt * 64 + t * 32 + ll] = ss;
    }
    __syncthreads();

    // ---- C-init: p = -log2e*||x_row||^2 in C/D layout ----
    // row = (reg&3) + 8*(reg>>2) + 4*(lane>>5)  [+ t*32]
    const int rb = 4 * lh;
    float16v p0, p1;
    #pragma unroll
    for (int i = 0; i < 16; ++i) {
        const int ri = rb + (i & 3) + 8 * (i >> 2);
        p0[i] = -QS * x2s[rt * 64 + ri];
        p1[i] = -QS * x2s[rt * 64 + 32 + ri];
    }

    const int zbase = rt * 64 + rb;
    const unsigned cboff = (unsigned)(wq * 64 + lane) * 32u;  // voffset, saddr
    const unsigned moff  = (unsigned)(wq * 32 + ll);

    // ---- FAST loop: branch-free, tracks run = max_c(mx_c - tq_c) ----
    int8v    pb0, pb1;
    unsigned mw0, mw1;
    float    run = -1.0e30f;

    pb0 = *(const int8v*)(cb + cboff);
    mw0 = hcw[moff];
    pb1 = *(const int8v*)(cb + cboff + 8192u);
    mw1 = hcw[moff + 128u];

    #pragma unroll 1
    for (int c = 0; c < NCHUNK; c += 2) {
        {   // slot 0 (chunk c)
            float16v a0 = MFMA(af0, pb0, p0);
            float16v a1 = MFMA(af1, pb0, p1);
            const float tq = __uint_as_float(mw0 & 0xffff0000u);
            if (c + 2 < NCHUNK) {
                pb0 = *(const int8v*)(cb + cboff + (unsigned)(c + 2) * 8192u);
                mw0 = hcw[moff + (unsigned)(c + 2) * 128u];
            }
            float mA, mB;
            MAX16(mA, a0);
            MAX16(mB, a1);
            run = fmaxf(run, fmaxf(mA, mB) - tq);
        }
        {   // slot 1 (chunk c+1)
            float16v a0 = MFMA(af0, pb1, p0);
            float16v a1 = MFMA(af1, pb1, p1);
            const float tq = __uint_as_float(mw1 & 0xffff0000u);
            if (c + 3 < NCHUNK) {
                pb1 = *(const int8v*)(cb + cboff + (unsigned)(c + 3) * 8192u);
                mw1 = hcw[moff + (unsigned)(c + 3) * 128u];
            }
            float mA, mB;
            MAX16(mA, a0);
            MAX16(mB, a1);
            run = fmaxf(run, fmaxf(mA, mB) - tq);
        }
    }

    // ---- SLOW verification pass: ~1% of waves; identical contributions ----
    if (__any(run > 0.0f)) {
        #pragma unroll 1
        for (int c = 0; c < NCHUNK; ++c) {
            int8v    b  = *(const int8v*)(cb + cboff + (unsigned)c * 8192u);
            unsigned mu = hcw[moff + (unsigned)c * 128u];
            float16v a0 = MFMA(af0, b, p0);
            float16v a1 = MFMA(af1, b, p1);
            const float tq  = __uint_as_float(mu & 0xffff0000u);
            const float wv_ = __uint_as_float(mu << 16);
            float mA, mB;
            MAX16(mA, a0);
            MAX16(mB, a1);
            if (__any(fmaxf(mA, mB) > tq)) {
                const float q = TSKIP - tq;          // = -log2e*||c||^2
                if (mA > tq) {
                    #pragma unroll
                    for (int i_ = 0; i_ < 16; ++i_)
                        atomicAdd(&zl[zbase + (i_ & 3) + 8 * (i_ >> 2)],
                                  wv_ * EXP2F(a0[i_] + q));
                }
                if (mB > tq) {
                    #pragma unroll
                    for (int i_ = 0; i_ < 16; ++i_)
                        atomicAdd(&zl[zbase + 32 + (i_ & 3) + 8 * (i_ >> 2)],
                                  wv_ * EXP2F(a1[i_] + q));
                }
            }
        }
    }

    // ---- combine, sigmoid, store ----
    __syncthreads();
    if (tid < 128) {
        const float z = zl[tid] + bptr[0];
        out[bid * 128 + tid] = 1.0f / (1.0f + EXP2F(-QS * z));
    }
}

// ================================ launcher =================================
extern "C" void kernel_launch(void* const* d_in, const int* in_sizes, int n_in,
                              void* d_out, int out_size, void* d_ws, size_t ws_size,
                              hipStream_t stream) {
    const float* x  = (const float*)d_in[0];   // [K, M]
    const float* xb = (const float*)d_in[1];   // [N, M]
    const float* w  = (const float*)d_in[2];   // [1, N]
    const float* b  = (const float*)d_in[3];   // [1]
    float* out = (float*)d_out;                // [K]

    char*     cb  = (char*)d_ws;                               // 256 KB fp8
    unsigned* hcw = (unsigned*)((char*)d_ws + NCENT * MFEAT);  // 16 KB packed meta

    rbf_prep<<<128 + NCENT / 4, 256, 0, stream>>>(xb, w, cb, hcw);
    rbf_main<<<KOBS / 128, 512, 0, stream>>>(x, cb, hcw, b, out);
}

// Round 12
// 96.436 us; speedup vs baseline: 1.0069x; 1.0069x over previous
//
#include <hip/hip_runtime.h>

// LogisticRegressionRBF: out[k] = sigmoid( sum_n w[n]*exp(-||x_k - c_n||^2) + b )
// K=65536, N=4096, M=64. fp32 in/out.
//
// R19: OCCUPANCY, done right this time. Ledger from 10 rounds: main is
// latency-bound (R15: halve waves -> +37%) and every 2-tile/wave variant is
// register-capped at 4 waves/SIMD (af16+p32+pb16+results32+misc ~ 114-124).
// R16 (1 tile/wave, 48 regs) failed because it dropped the TIGHT screen, not
// because of tile size: loose screen fire-rate ~1-3% x 32-lane contended
// atomics ate the gain. R18 failed by duplicating the loop (regs > 128 ->
// 3 waves/SIMD). This round:
//   - 1 tile (32x32) per wave, TIGHT screen kept: af 8 + p 16 + d 16 +
//     pb ping-pong 16 + misc ~ 70-80 regs -> 6 waves/SIMD = 24 waves/CU
//     (1.5x TLP vs all previous mains)
//   - block 256 = 4 waves (4 center-quarters), 32 rows/block, grid 2048
//     (8 blocks/CU -> fine-grain scheduling, no tail cliff)
//   - __launch_bounds__(256, 6) forces <=85 regs; WRITE_SIZE is the spill
//     tripwire (expect ~0.5 MB; >1 MB => revert bound)
//   - loop = R13's proven body per tile: MFMA(C=-log2e*x^2), MAX16, one
//     ballot, rare path (~2e-4) exact exp2+LDS-atomic
// Readout: occupancy >=65% + main ~16-22 -> total ~74-80. If occupancy rises
// but main doesn't move: latency theory dead, roofline argument next.

#define KOBS 65536
#define NCENT 4096
#define MFEAT 64
#define NCHUNK 32                    // 4096 / 128 centers per chunk

#define SCALE_A 2.8853900817779268f  // 2*log2(e)
#define QS      1.4426950408889634f  // log2(e)
#define TSKIP   -60.0f

typedef __attribute__((ext_vector_type(4)))  float float4v;
typedef __attribute__((ext_vector_type(16))) float float16v;
typedef __attribute__((ext_vector_type(8)))  int   int8v;

#if __has_builtin(__builtin_amdgcn_exp2f)
#define EXP2F(x) __builtin_amdgcn_exp2f(x)
#else
#define EXP2F(x) exp2f(x)
#endif

static __device__ inline unsigned f2bfu(float f) {
    unsigned u = __float_as_uint(f);
    return (u + 0x7fffu + ((u >> 16) & 1u)) >> 16;
}

#define MFMA(A, B, C) __builtin_amdgcn_mfma_scale_f32_32x32x64_f8f6f4( \
    (A), (B), (C), 0, 0, 0, 0x7f7f7f7f, 0, 0x7f7f7f7f)

// 16-value max tree (max3-fusable triples)
#define MAX16(DST, AV) do {                                        \
    float t0_ = fmaxf(fmaxf((AV)[0],  (AV)[1]),  (AV)[2]);         \
    float t1_ = fmaxf(fmaxf((AV)[3],  (AV)[4]),  (AV)[5]);         \
    float t2_ = fmaxf(fmaxf((AV)[6],  (AV)[7]),  (AV)[8]);         \
    float t3_ = fmaxf(fmaxf((AV)[9],  (AV)[10]), (AV)[11]);        \
    float t4_ = fmaxf(fmaxf((AV)[12], (AV)[13]), (AV)[14]);        \
    DST = fmaxf(fmaxf(fmaxf(t0_, t1_), t2_),                       \
                fmaxf(fmaxf(t3_, t4_), (AV)[15]));                 \
} while (0)

// ================================ prep =====================================
// Blocks [0,128): transpose+quantize xb fp32 -> fp8 e4m3 B-fragments.
// Blocks [128,1152): hcw[n] = { bf16(TSKIP + log2e*||c_n||^2) | bf16(w[n]) }.
__global__ __launch_bounds__(256) void rbf_prep(
    const float* __restrict__ xb, const float* __restrict__ w,
    char* __restrict__ cb, unsigned* __restrict__ hcw) {
    const int bid = blockIdx.x;
    const int tid = threadIdx.x;
    if (bid < 128) {
        const int o      = bid * 256 + tid;   // (center, k-octet), [0, 32768)
        const int col    = o >> 3;            // center index
        const int joct   = o & 7;             // k0 = joct*8
        const int c      = col >> 7;          // chunk
        const int w4     = (col >> 5) & 3;    // wave-quarter within chunk
        const int lanelo = col & 31;
        const int l      = lanelo + (joct >> 2) * 32;  // lane (k-half select)
        const int j0     = (joct & 3) * 8;             // byte offset in 32B
        const float* src = xb + col * MFEAT + joct * 8;
        float4v v0 = *(const float4v*)(src);
        float4v v1 = *(const float4v*)(src + 4);
        int lo = __builtin_amdgcn_cvt_pk_fp8_f32(v0[0], v0[1], 0, false);
        lo     = __builtin_amdgcn_cvt_pk_fp8_f32(v0[2], v0[3], lo, true);
        int hi = __builtin_amdgcn_cvt_pk_fp8_f32(v1[0], v1[1], 0, false);
        hi     = __builtin_amdgcn_cvt_pk_fp8_f32(v1[2], v1[3], hi, true);
        unsigned long long pk = (unsigned long long)(unsigned)lo |
                                ((unsigned long long)(unsigned)hi << 32);
        *(unsigned long long*)(cb + (size_t)((c * 4 + w4) * 64 + l) * 32 + j0) = pk;
    } else {
        const int row  = (bid - 128) * 4 + (tid >> 6);
        const int lane = tid & 63;
        float v = xb[row * MFEAT + lane];
        float s = v * v;
        #pragma unroll
        for (int off = 32; off > 0; off >>= 1) s += __shfl_xor(s, off, 64);
        if (lane == 0)
            hcw[row] = (f2bfu(TSKIP + QS * s) << 16) | f2bfu(w[row]);
    }
}

// ================================ main =====================================
// grid 2048 x block 256. Block: 32 output rows; 4 waves = 4 center quarters.
__global__ __launch_bounds__(256, 6) void rbf_main(
    const float* __restrict__ x, const char* __restrict__ cb,
    const unsigned* __restrict__ hcw, const float* __restrict__ bptr,
    float* __restrict__ out) {
    __shared__ float x2s[32];
    __shared__ float zl[32];

    const int tid  = threadIdx.x;
    const int wq   = tid >> 6;       // center quarter (wave id)
    const int lane = tid & 63;
    const int ll   = lane & 31;
    const int lh   = lane >> 5;
    const int bid  = (int)blockIdx.x;
    const int rb   = 4 * lh;

    if (tid < 32) zl[tid] = 0.0f;

    // ---- A fragment (fp8, pre-scaled by 2*log2e) + row norms ----
    // A-frag layout 32x32x64: lane l holds row l&31, k = (l>>5)*32 + byte.
    int8v af;
    {
        const float* xr = x + (size_t)(bid * 32 + ll) * MFEAT + lh * 32;
        float ss = 0.0f;
        #pragma unroll
        for (int rg = 0; rg < 8; ++rg) {
            float4v v = *(const float4v*)(xr + rg * 4);
            ss = fmaf(v[0], v[0], ss); ss = fmaf(v[1], v[1], ss);
            ss = fmaf(v[2], v[2], ss); ss = fmaf(v[3], v[3], ss);
            int pk = __builtin_amdgcn_cvt_pk_fp8_f32(
                SCALE_A * v[0], SCALE_A * v[1], 0, false);
            pk = __builtin_amdgcn_cvt_pk_fp8_f32(
                SCALE_A * v[2], SCALE_A * v[3], pk, true);
            af[rg] = pk;
        }
        ss += __shfl_xor(ss, 32, 64);   // partner lane has other k-half
        if (wq == 0 && lh == 0) x2s[ll] = ss;
    }
    __syncthreads();

    // ---- C-init: p = -log2e*||x_row||^2 in C/D layout ----
    // row = (reg&3) + 8*(reg>>2) + 4*(lane>>5)
    float16v p;
    #pragma unroll
    for (int i = 0; i < 16; ++i)
        p[i] = -QS * x2s[rb + (i & 3) + 8 * (i >> 2)];

    // ---- main loop: ping-pong prefetch, one 32x32x64 MFMA per step ----
    const unsigned cboff = (unsigned)(wq * 64 + lane) * 32u;  // voffset, saddr
    const unsigned moff  = (unsigned)(wq * 32 + ll);

    int8v    pb0, pb1;
    unsigned mw0, mw1;

    pb0 = *(const int8v*)(cb + cboff);
    mw0 = hcw[moff];
    pb1 = *(const int8v*)(cb + cboff + 8192u);
    mw1 = hcw[moff + 128u];

    #define STEP(C, PB, MW) do {                                           \
        const float tq  = __uint_as_float(MW & 0xffff0000u);               \
        const float wv_ = __uint_as_float(MW << 16);                       \
        float16v d = MFMA(af, PB, p);                                      \
        if ((C) + 2 < NCHUNK) {                                            \
            PB = *(const int8v*)(cb + cboff + (unsigned)((C) + 2) * 8192u);\
            MW = hcw[moff + (unsigned)((C) + 2) * 128u];                   \
        }                                                                  \
        float mx;                                                          \
        MAX16(mx, d);                                                      \
        if (__any(mx > tq)) {              /* rare: ~2e-4 of tiles */      \
            if (mx > tq) {                                                 \
                const float q = TSKIP - tq;    /* = -log2e*||c||^2 */      \
                _Pragma("unroll")                                          \
                for (int i_ = 0; i_ < 16; ++i_)                            \
                    atomicAdd(&zl[rb + (i_ & 3) + 8 * (i_ >> 2)],          \
                              wv_ * EXP2F(d[i_] + q));                     \
            }                                                              \
        }                                                                  \
    } while (0)

    #pragma unroll 1
    for (int c = 0; c < NCHUNK; c += 2) {
        STEP(c,     pb0, mw0);
        STEP(c + 1, pb1, mw1);
    }

    #undef STEP

    // ---- combine, sigmoid, store ----
    __syncthreads();
    if (tid < 32) {
        const float z = zl[tid] + bptr[0];
        out[bid * 32 + tid] = 1.0f / (1.0f + EXP2F(-QS * z));
    }
}

// ================================ launcher =================================
extern "C" void kernel_launch(void* const* d_in, const int* in_sizes, int n_in,
                              void* d_out, int out_size, void* d_ws, size_t ws_size,
                              hipStream_t stream) {
    const float* x  = (const float*)d_in[0];   // [K, M]
    const float* xb = (const float*)d_in[1];   // [N, M]
    const float* w  = (const float*)d_in[2];   // [1, N]
    const float* b  = (const float*)d_in[3];   // [1]
    float* out = (float*)d_out;                // [K]

    char*     cb  = (char*)d_ws;                               // 256 KB fp8
    unsigned* hcw = (unsigned*)((char*)d_ws + NCENT * MFEAT);  // 16 KB packed meta

    rbf_prep<<<128 + NCENT / 4, 256, 0, stream>>>(xb, w, cb, hcw);
    rbf_main<<<KOBS / 32, 256, 0, stream>>>(x, cb, hcw, b, out);
}

// Round 13
// 95.745 us; speedup vs baseline: 1.0141x; 1.0072x over previous
//
#include <hip/hip_runtime.h>

// LogisticRegressionRBF: out[k] = sigmoid( sum_n w[n]*exp(-||x_k - c_n||^2) + b )
// K=65536, N=4096, M=64. fp32 in/out.
//
// R20: center-split + LDS-resident B + global-z accumulation.
// Ledger: R13-R19 showed (a) latency term hidden by TLP (R15 fit:
// T ~ 16 + 224/waves_per_CU), (b) 16 waves/CU register cap caused by in-loop
// GLOBAL B-loads (prefetch regs + 2-tile amortization), (c) 1-tile/wave with
// global loads regressed (load:compute doubled, R19). Fix all three at once:
//   - block = 256 rows x 512 centers (split s = bid&7). Split's B-panel =
//     32 KB fp8 -> LDS, staged ONCE in prologue. Main loop (16 iters) is
//     pure ds_read -> MFMA -> screen: no global loads, no barriers, no
//     prefetch registers.
//   - regs: af 8 + p 16 + d 16 + b 8 + misc ~ 65-70 -> __launch_bounds__
//     (512,6); LDS 35 KB -> 3-4 blocks/CU -> 24-32 waves/CU (vs 16).
//   - rows span blocks (8 splits/row): z = global fp32 array (in ws, zeroed
//     by prep); rare path (~2e-4 tiles, ~50/kernel) global-atomicAdds;
//     tiny 3rd kernel does sigmoid. Per-block L2 traffic 512->34 KB.
//   - known cost: 64 B LDS stride -> ~2x on the 2 ds_read_b128/iter
//     (SQ_LDS_BANK_CONFLICT nonzero BY DESIGN, hidden under MFMA).
// Readout: main ~16-22 -> total ~74-80. If main ~30 despite LDS loop +
// 24-32 waves: serial floor is MFMA-result latency -> ceiling argument.

#define KOBS 65536
#define NCENT 4096
#define MFEAT 64
#define NSPLIT 8
#define SPLITC 512                   // centers per split
#define NT 16                        // col-tiles (of 32 centers) per wave

#define SCALE_A 2.8853900817779268f  // 2*log2(e)
#define QS      1.4426950408889634f  // log2(e)
#define TSKIP   -60.0f

typedef __attribute__((ext_vector_type(4)))  float    float4v;
typedef __attribute__((ext_vector_type(16))) float    float16v;
typedef __attribute__((ext_vector_type(8)))  int      int8v;
typedef __attribute__((ext_vector_type(4)))  unsigned uint4v;

#if __has_builtin(__builtin_amdgcn_exp2f)
#define EXP2F(x) __builtin_amdgcn_exp2f(x)
#else
#define EXP2F(x) exp2f(x)
#endif

static __device__ inline unsigned f2bfu(float f) {
    unsigned u = __float_as_uint(f);
    return (u + 0x7fffu + ((u >> 16) & 1u)) >> 16;
}

#define MFMA(A, B, C) __builtin_amdgcn_mfma_scale_f32_32x32x64_f8f6f4( \
    (A), (B), (C), 0, 0, 0, 0x7f7f7f7f, 0, 0x7f7f7f7f)

// 16-value max tree (max3-fusable triples)
#define MAX16(DST, AV) do {                                        \
    float t0_ = fmaxf(fmaxf((AV)[0],  (AV)[1]),  (AV)[2]);         \
    float t1_ = fmaxf(fmaxf((AV)[3],  (AV)[4]),  (AV)[5]);         \
    float t2_ = fmaxf(fmaxf((AV)[6],  (AV)[7]),  (AV)[8]);         \
    float t3_ = fmaxf(fmaxf((AV)[9],  (AV)[10]), (AV)[11]);        \
    float t4_ = fmaxf(fmaxf((AV)[12], (AV)[13]), (AV)[14]);        \
    DST = fmaxf(fmaxf(fmaxf(t0_, t1_), t2_),                       \
                fmaxf(fmaxf(t3_, t4_), (AV)[15]));                 \
} while (0)

// ================================ prep =====================================
// Blocks [0,128):       cb[col*64 + j] = fp8(xb[col][j])   (center-major, K-linear)
// Blocks [128,1152):    hcw[n] = { bf16(TSKIP + log2e*||c_n||^2) | bf16(w[n]) }
// Blocks [1152,1216):   zero the global z accumulator (65536 fp32)
__global__ __launch_bounds__(256) void rbf_prep(
    const float* __restrict__ xb, const float* __restrict__ w,
    char* __restrict__ cb, unsigned* __restrict__ hcw, float* __restrict__ z) {
    const int bid = blockIdx.x;
    const int tid = threadIdx.x;
    if (bid < 128) {
        const int o    = bid * 256 + tid;     // (center, k-octet), [0, 32768)
        const int col  = o >> 3;
        const int joct = o & 7;
        const float* src = xb + col * MFEAT + joct * 8;
        float4v v0 = *(const float4v*)(src);
        float4v v1 = *(const float4v*)(src + 4);
        int lo = __builtin_amdgcn_cvt_pk_fp8_f32(v0[0], v0[1], 0, false);
        lo     = __builtin_amdgcn_cvt_pk_fp8_f32(v0[2], v0[3], lo, true);
        int hi = __builtin_amdgcn_cvt_pk_fp8_f32(v1[0], v1[1], 0, false);
        hi     = __builtin_amdgcn_cvt_pk_fp8_f32(v1[2], v1[3], hi, true);
        unsigned long long pk = (unsigned long long)(unsigned)lo |
                                ((unsigned long long)(unsigned)hi << 32);
        *(unsigned long long*)(cb + (size_t)col * 64 + joct * 8) = pk;
    } else if (bid < 128 + 1024) {
        const int row  = (bid - 128) * 4 + (tid >> 6);
        const int lane = tid & 63;
        float v = xb[row * MFEAT + lane];
        float s = v * v;
        #pragma unroll
        for (int off = 32; off > 0; off >>= 1) s += __shfl_xor(s, off, 64);
        if (lane == 0)
            hcw[row] = (f2bfu(TSKIP + QS * s) << 16) | f2bfu(w[row]);
    } else {
        float4v zero = {0.0f, 0.0f, 0.0f, 0.0f};
        ((float4v*)z)[(bid - 1152) * 256 + tid] = zero;
    }
}

// ================================ main =====================================
// grid 2048 x block 512. Block: 256 rows x 512 centers (split s = bid&7).
// Wave wv owns rows rowbase + wv*32 .. +31; loops 16 col-tiles of 32 centers.
__global__ __launch_bounds__(512, 6) void rbf_main(
    const float* __restrict__ x, const char* __restrict__ cb,
    const unsigned* __restrict__ hcw, float* __restrict__ z) {
    __shared__ char     cbs[SPLITC * 64];    // 32 KB B-panel
    __shared__ unsigned meta_s[SPLITC];      // 2 KB
    __shared__ float    x2s[256];            // 1 KB

    const int tid  = threadIdx.x;
    const int wv   = tid >> 6;
    const int lane = tid & 63;
    const int ll   = lane & 31;
    const int lh   = lane >> 5;
    const int bid  = (int)blockIdx.x;
    const int s    = bid & 7;                // center split
    const int rowbase = (bid >> 3) * 256;
    const int rb   = 4 * lh;

    // ---- stage this split's B-panel (issue loads first, writes later) ----
    const char* gsrc = cb + (size_t)s * (SPLITC * 64) + (size_t)tid * 64;
    uint4v g0 = ((const uint4v*)gsrc)[0];
    uint4v g1 = ((const uint4v*)gsrc)[1];
    uint4v g2 = ((const uint4v*)gsrc)[2];
    uint4v g3 = ((const uint4v*)gsrc)[3];
    unsigned mstg = (tid < SPLITC) ? hcw[s * SPLITC + tid] : 0u;

    // ---- A fragment (fp8, pre-scaled by 2*log2e) + row norms ----
    // A-frag layout 32x32x64: lane l holds row l&31, k = (l>>5)*32 + byte.
    int8v af;
    {
        const float* xr = x + (size_t)(rowbase + wv * 32 + ll) * MFEAT + lh * 32;
        float ss = 0.0f;
        #pragma unroll
        for (int rg = 0; rg < 8; ++rg) {
            float4v v = *(const float4v*)(xr + rg * 4);
            ss = fmaf(v[0], v[0], ss); ss = fmaf(v[1], v[1], ss);
            ss = fmaf(v[2], v[2], ss); ss = fmaf(v[3], v[3], ss);
            int pk = __builtin_amdgcn_cvt_pk_fp8_f32(
                SCALE_A * v[0], SCALE_A * v[1], 0, false);
            pk = __builtin_amdgcn_cvt_pk_fp8_f32(
                SCALE_A * v[2], SCALE_A * v[3], pk, true);
            af[rg] = pk;
        }
        ss += __shfl_xor(ss, 32, 64);   // partner lane has other k-half
        if (lh == 0) x2s[wv * 32 + ll] = ss;
    }

    // ---- LDS writes for the staged panel + meta ----
    {
        uint4v* ldst = (uint4v*)(cbs + tid * 64);
        ldst[0] = g0; ldst[1] = g1; ldst[2] = g2; ldst[3] = g3;
        if (tid < SPLITC) meta_s[tid] = mstg;
    }
    __syncthreads();

    // ---- C-init: p = -log2e*||x_row||^2 in C/D layout ----
    // row = (reg&3) + 8*(reg>>2) + 4*(lane>>5)
    float16v p;
    #pragma unroll
    for (int i = 0; i < 16; ++i)
        p[i] = -QS * x2s[wv * 32 + rb + (i & 3) + 8 * (i >> 2)];

    // ---- main loop: pure LDS -> MFMA -> screen; no barriers ----
    const int   zrow = rowbase + wv * 32 + rb;
    const char* cbl  = cbs + (unsigned)ll * 64 + (unsigned)lh * 32;

    #pragma unroll 2
    for (int t = 0; t < NT; ++t) {
        const char* bp = cbl + t * 2048;     // (t*32 + ll)*64 + lh*32
        uint4v blo = *(const uint4v*)(bp);
        uint4v bhi = *(const uint4v*)(bp + 16);
        int8v b;
        b[0] = (int)blo[0]; b[1] = (int)blo[1]; b[2] = (int)blo[2]; b[3] = (int)blo[3];
        b[4] = (int)bhi[0]; b[5] = (int)bhi[1]; b[6] = (int)bhi[2]; b[7] = (int)bhi[3];
        const unsigned mu = meta_s[t * 32 + ll];
        const float tq  = __uint_as_float(mu & 0xffff0000u);
        const float wv_ = __uint_as_float(mu << 16);

        float16v d = MFMA(af, b, p);

        float mx;
        MAX16(mx, d);
        if (__any(mx > tq)) {                // rare: ~2e-4 of tiles
            if (mx > tq) {
                const float q = TSKIP - tq;  // = -log2e*||c||^2
                #pragma unroll
                for (int i_ = 0; i_ < 16; ++i_)
                    atomicAdd(&z[zrow + (i_ & 3) + 8 * (i_ >> 2)],
                              wv_ * EXP2F(d[i_] + q));
            }
        }
    }
}

// ================================ epilogue =================================
// grid 64 x block 256: out[k] = sigmoid(z[k] + b), float4 per thread.
__global__ __launch_bounds__(256) void rbf_epi(
    const float* __restrict__ z, const float* __restrict__ bptr,
    float* __restrict__ out) {
    const int i = blockIdx.x * 256 + threadIdx.x;
    const float bb = bptr[0];
    float4v zz = ((const float4v*)z)[i];
    float4v o;
    #pragma unroll
    for (int j = 0; j < 4; ++j)
        o[j] = 1.0f / (1.0f + EXP2F(-QS * (zz[j] + bb)));
    ((float4v*)out)[i] = o;
}

// ================================ launcher =================================
extern "C" void kernel_launch(void* const* d_in, const int* in_sizes, int n_in,
                              void* d_out, int out_size, void* d_ws, size_t ws_size,
                              hipStream_t stream) {
    const float* x  = (const float*)d_in[0];   // [K, M]
    const float* xb = (const float*)d_in[1];   // [N, M]
    const float* w  = (const float*)d_in[2];   // [1, N]
    const float* b  = (const float*)d_in[3];   // [1]
    float* out = (float*)d_out;                // [K]

    char*     cb  = (char*)d_ws;                                   // 256 KB fp8
    unsigned* hcw = (unsigned*)((char*)d_ws + NCENT * MFEAT);      // 16 KB meta
    float*    z   = (float*)((char*)d_ws + NCENT * MFEAT + NCENT * 4);  // 256 KB

    rbf_prep<<<128 + 1024 + 64, 256, 0, stream>>>(xb, w, cb, hcw, z);
    rbf_main<<<(KOBS / 256) * NSPLIT, 512, 0, stream>>>(x, cb, hcw, z);
    rbf_epi<<<KOBS / 1024, 256, 0, stream>>>(z, b, out);
}